// Round 2
// baseline (454.192 us; speedup 1.0000x reference)
//
#include <hip/hip_runtime.h>
#include <hip/hip_bf16.h>

#define NN 50000
#define NE 800000
#define DIN 128
#define DEIN 32
#define PD 192          // P row: [0:64) f_ni, [64:128) f_nj, [128:192) h_src(node proj)
#define NEG_SLOPE 0.2f

typedef __bf16 bf16x8 __attribute__((ext_vector_type(8)));
typedef float f32x4 __attribute__((ext_vector_type(4)));
using bf16 = __hip_bfloat16;

__device__ inline bf16x8 load8_f32_to_bf16(const float* p) {
    f32x4 a = *reinterpret_cast<const f32x4*>(p);
    f32x4 b = *reinterpret_cast<const f32x4*>(p + 4);
    bf16x8 r;
#pragma unroll
    for (int j = 0; j < 4; j++) {
        r[j]     = (__bf16)a[j];
        r[j + 4] = (__bf16)b[j];
    }
    return r;
}

// ---------------- K1: fused node GEMM: P = nfeats @ [W_ni | W_nj | W_node] ----------------
// wave = one 16-col tile, 5 consecutive 16-row tiles. 625 row-chunks x 12 col-tiles
// = 7500 waves = 1875 blocks of 256.
__global__ __launch_bounds__(256) void k_node_gemm(
    const float* __restrict__ nfeats,
    const float* __restrict__ Wni, const float* __restrict__ Wnj,
    const float* __restrict__ Wnode,
    bf16* __restrict__ P)
{
    const int lane = threadIdx.x & 63;
    const int wid  = threadIdx.x >> 6;
    const int waveId = blockIdx.x * 4 + wid;
    const int colTile = waveId % 12;
    const int chunk   = waveId / 12;           // 0..624
    const int c0 = colTile * 16;               // within 192
    const float* W; int cw;
    if (c0 < 64)       { W = Wni;   cw = c0; }
    else if (c0 < 128) { W = Wnj;   cw = c0 - 64; }
    else               { W = Wnode; cw = c0 - 128; }
    const int lo = lane & 15;   // A row / B col / D col
    const int hi = lane >> 4;   // k-group
    // B frags: B[k][col], k = kk*32 + hi*8 + j, col = cw+lo   (W is [128][64] row-major f32)
    bf16x8 bfrag[4];
#pragma unroll
    for (int kk = 0; kk < 4; kk++)
#pragma unroll
        for (int j = 0; j < 8; j++)
            bfrag[kk][j] = (__bf16)W[(kk*32 + hi*8 + j)*64 + cw + lo];

    const int n0 = chunk * 80;
#pragma unroll
    for (int rt = 0; rt < 5; rt++) {
        const int nbase = n0 + rt*16;
        f32x4 acc = {0.f, 0.f, 0.f, 0.f};
#pragma unroll
        for (int kk = 0; kk < 4; kk++) {
            bf16x8 afrag = load8_f32_to_bf16(
                &nfeats[(size_t)(nbase + lo)*DIN + kk*32 + hi*8]);
            acc = __builtin_amdgcn_mfma_f32_16x16x32_bf16(afrag, bfrag[kk], acc, 0, 0, 0);
        }
#pragma unroll
        for (int r = 0; r < 4; r++) {
            const int rr = hi*4 + r;   // D row
            P[(size_t)(nbase + rr)*PD + c0 + lo] = __float2bfloat16(acc[r]);
        }
    }
}

// ---------------- CSR build ----------------
__global__ void k_zero(int* __restrict__ counts, int* __restrict__ cursor, int n) {
    int i = blockIdx.x * blockDim.x + threadIdx.x;
    if (i < n) { counts[i] = 0; cursor[i] = 0; }
}

__global__ void k_hist(const int* __restrict__ dst, int* __restrict__ counts, int e) {
    int i = blockIdx.x * blockDim.x + threadIdx.x;
    if (i < e) atomicAdd(&counts[dst[i]], 1);
}

// single-block exclusive scan, chunk = 8192 (8 per thread), wave-level scan
__global__ __launch_bounds__(1024) void k_scan(const int* __restrict__ counts,
                                               int* __restrict__ offsets, int n) {
    __shared__ int wsum[16];
    __shared__ int chunk_carry;
    if (threadIdx.x == 0) chunk_carry = 0;
    __syncthreads();
    const int lane = threadIdx.x & 63;
    const int wid  = threadIdx.x >> 6;
    for (int base = 0; base < n; base += 8192) {
        const int i0 = base + threadIdx.x * 8;
        int v[8], tsum = 0;
#pragma unroll
        for (int j = 0; j < 8; j++) {
            int idx = i0 + j;
            v[j] = (idx < n) ? counts[idx] : 0;
            tsum += v[j];
        }
        int sc = tsum;                    // inclusive wave scan of per-thread sums
#pragma unroll
        for (int s = 1; s < 64; s <<= 1) {
            int t = __shfl_up(sc, s);
            if (lane >= s) sc += t;
        }
        if (lane == 63) wsum[wid] = sc;
        __syncthreads();
        int woff = 0;
        for (int k = 0; k < wid; k++) woff += wsum[k];
        int run = chunk_carry + woff + (sc - tsum);   // exclusive prefix for this thread
#pragma unroll
        for (int j = 0; j < 8; j++) {
            int idx = i0 + j;
            if (idx < n) offsets[idx] = run;
            run += v[j];
        }
        __syncthreads();
        if (threadIdx.x == 1023) chunk_carry += woff + sc;
        __syncthreads();
    }
    if (threadIdx.x == 0) offsets[n] = chunk_carry;
}

__global__ void k_scatter(const int* __restrict__ dst, const int* __restrict__ offsets,
                          int* __restrict__ cursor, int* __restrict__ eidx, int e) {
    int i = blockIdx.x * blockDim.x + threadIdx.x;
    if (i < e) {
        int d = dst[i];
        int p = atomicAdd(&cursor[d], 1);
        eidx[offsets[d] + p] = i;
    }
}

// ---------------- K2: fused edge stage ----------------
// block = 4 waves, each wave = 16 edges x 64 cols (4 col-tiles, one MFMA each).
// f_out = leaky(efeats@Wf + P_i[src] + P_j[dst] + bias); el[e][h] = sum_f f_out*attn
__global__ __launch_bounds__(256) void k_edge(
    const float* __restrict__ efeats,
    const float* __restrict__ Wf,     // [32][64] f32
    const float* __restrict__ attn,   // [64] f32
    const float* __restrict__ bias,   // [64] f32
    const bf16* __restrict__ P,       // [NN][192]
    const int* __restrict__ src, const int* __restrict__ dst,
    float* __restrict__ f_out,        // [NE][64] f32
    float* __restrict__ el)           // [NE][4]
{
    const int lane = threadIdx.x & 63;
    const int wid  = threadIdx.x >> 6;
    const int lo = lane & 15, hi = lane >> 4;
    const int e0 = blockIdx.x * 64 + wid * 16;

    bf16x8 afrag = load8_f32_to_bf16(&efeats[(size_t)(e0 + lo)*DEIN + hi*8]);

    int es[4], ed[4];
#pragma unroll
    for (int r = 0; r < 4; r++) {
        es[r] = src[e0 + hi*4 + r];
        ed[r] = dst[e0 + hi*4 + r];
    }
#pragma unroll
    for (int ct = 0; ct < 4; ct++) {
        bf16x8 bfrag;
#pragma unroll
        for (int j = 0; j < 8; j++)
            bfrag[j] = (__bf16)Wf[(hi*8 + j)*64 + ct*16 + lo];
        f32x4 acc = {0.f, 0.f, 0.f, 0.f};
        acc = __builtin_amdgcn_mfma_f32_16x16x32_bf16(afrag, bfrag, acc, 0, 0, 0);

        const int c = ct*16 + lo;
        const float att = attn[c];
        const float bs  = bias[c];
#pragma unroll
        for (int r = 0; r < 4; r++) {
            const int er = e0 + hi*4 + r;
            float v = acc[r]
                    + __bfloat162float(P[(size_t)es[r]*PD + c])
                    + __bfloat162float(P[(size_t)ed[r]*PD + 64 + c])
                    + bs;
            v = v > 0.f ? v : NEG_SLOPE * v;
            f_out[(size_t)er*64 + c] = v;
            float t = v * att;                 // logit partial, reduce over f (16 lanes)
            t += __shfl_xor(t, 1);
            t += __shfl_xor(t, 2);
            t += __shfl_xor(t, 4);
            t += __shfl_xor(t, 8);
            if (lo == 0) el[(size_t)er*4 + ct] = t;
        }
    }
}

// ---------------- K4: per-dst-node online softmax + weighted aggregation ----------------
// one wave per node; lane = h*16+f accumulates h_out[n][h][f]
__global__ __launch_bounds__(256) void k_aggregate(
    const int* __restrict__ offsets, const int* __restrict__ eidx,
    const int* __restrict__ src, const float* __restrict__ el,
    const bf16* __restrict__ P, float* __restrict__ h_out)
{
    const int lane = threadIdx.x & 63;
    const int wid  = threadIdx.x >> 6;
    const int n = blockIdx.x * 4 + wid;
    if (n >= NN) return;
    const int h = lane >> 4;
    const int off0 = offsets[n], off1 = offsets[n + 1];
    float m = -3.0e38f, den = 0.f, acc = 0.f;
    for (int t = off0; t < off1; t++) {
        const int e = eidx[t];
        const int s = src[e];
        const float lv = el[(size_t)e*4 + h];
        const float p  = __bfloat162float(P[(size_t)s*PD + 128 + lane]);
        const float nm = fmaxf(m, lv);
        const float scale = __expf(m - nm);
        const float w = __expf(lv - nm);
        den = den * scale + w;
        acc = acc * scale + w * p;
        m = nm;
    }
    const float o = (off1 > off0) ? acc / den : 0.f;
    h_out[(size_t)n*64 + lane] = o;
}

extern "C" void kernel_launch(void* const* d_in, const int* in_sizes, int n_in,
                              void* d_out, int out_size, void* d_ws, size_t ws_size,
                              hipStream_t stream) {
    const float* nfeats = (const float*)d_in[0];
    const float* efeats = (const float*)d_in[1];
    const float* Wni    = (const float*)d_in[2];
    const float* Wnj    = (const float*)d_in[3];
    const float* Wfij   = (const float*)d_in[4];
    const float* Wnode  = (const float*)d_in[5];
    const float* attn   = (const float*)d_in[6];
    const float* bias   = (const float*)d_in[7];
    const int*   src    = (const int*)d_in[8];
    const int*   dst    = (const int*)d_in[9];

    float* h_out = (float*)d_out;                           // [NN*64]
    float* f_out = (float*)d_out + (size_t)NN * 64;         // [NE*64]

    char* ws = (char*)d_ws;
    size_t off = 0;
    auto carve = [&](size_t bytes) -> void* {
        void* p = ws + off;
        off = (off + bytes + 255) & ~(size_t)255;
        return p;
    };
    bf16*  P       = (bf16*) carve((size_t)NN * PD * sizeof(bf16));
    float* el      = (float*)carve((size_t)NE * 4 * sizeof(float));
    int*   counts  = (int*)  carve((size_t)NN * sizeof(int));
    int*   cursor  = (int*)  carve((size_t)NN * sizeof(int));
    int*   offsets = (int*)  carve((size_t)(NN + 1) * sizeof(int));
    int*   eidx    = (int*)  carve((size_t)NE * sizeof(int));
    (void)ws_size; (void)in_sizes; (void)n_in; (void)out_size;

    hipLaunchKernelGGL(k_node_gemm, dim3(1875), dim3(256), 0, stream,
                       nfeats, Wni, Wnj, Wnode, P);
    hipLaunchKernelGGL(k_zero, dim3((NN + 255) / 256), dim3(256), 0, stream,
                       counts, cursor, NN);
    hipLaunchKernelGGL(k_hist, dim3((NE + 255) / 256), dim3(256), 0, stream,
                       dst, counts, NE);
    hipLaunchKernelGGL(k_scan, dim3(1), dim3(1024), 0, stream,
                       counts, offsets, NN);
    hipLaunchKernelGGL(k_scatter, dim3((NE + 255) / 256), dim3(256), 0, stream,
                       dst, offsets, cursor, eidx, NE);
    hipLaunchKernelGGL(k_edge, dim3(NE / 64), dim3(256), 0, stream,
                       efeats, Wfij, attn, bias, P, src, dst, f_out, el);
    hipLaunchKernelGGL(k_aggregate, dim3((NN + 3) / 4), dim3(256), 0, stream,
                       offsets, eidx, src, el, P, h_out);
}

// Round 3
// 401.476 us; speedup vs baseline: 1.1313x; 1.1313x over previous
//
#include <hip/hip_runtime.h>
#include <hip/hip_bf16.h>

#define NN 50000
#define NE 800000
#define DIN 128
#define DEIN 32
#define PD 192          // P row: [0:64) f_ni, [64:128) f_nj, [128:192) h_src(node proj)
#define NEG_SLOPE 0.2f

typedef __bf16 bf16x8 __attribute__((ext_vector_type(8)));
typedef float f32x4 __attribute__((ext_vector_type(4)));
using bf16 = __hip_bfloat16;

__device__ inline bf16x8 load8_f32_to_bf16(const float* p) {
    f32x4 a = *reinterpret_cast<const f32x4*>(p);
    f32x4 b = *reinterpret_cast<const f32x4*>(p + 4);
    bf16x8 r;
#pragma unroll
    for (int j = 0; j < 4; j++) {
        r[j]     = (__bf16)a[j];
        r[j + 4] = (__bf16)b[j];
    }
    return r;
}

__device__ inline void async_copy16(const void* g, void* lds) {
    __builtin_amdgcn_global_load_lds(
        (const __attribute__((address_space(1))) void*)g,
        (__attribute__((address_space(3))) void*)lds, 16, 0, 0);
}

// ---------------- K1: P = nfeats @ [W_ni | W_nj | W_node], LDS-staged W ----------------
// block = 64 rows (4 waves x 16), loops 12 col-tiles; nfeats read exactly once.
__global__ __launch_bounds__(256) void k_node_gemm(
    const float* __restrict__ nfeats,
    const float* __restrict__ Wni, const float* __restrict__ Wnj,
    const float* __restrict__ Wnode,
    bf16* __restrict__ P)
{
    __shared__ __align__(16) __bf16 sW[16][136];   // [col][k], pad->2-way-free
    const int lane = threadIdx.x & 63;
    const int wid  = threadIdx.x >> 6;
    const int lo = lane & 15, hi = lane >> 4;
    const int rbase = blockIdx.x * 64 + wid * 16;

    bf16x8 afrag[4];
#pragma unroll
    for (int kk = 0; kk < 4; kk++) {
        int row = rbase + lo; if (row >= NN) row = NN - 1;
        afrag[kk] = load8_f32_to_bf16(&nfeats[(size_t)row*DIN + kk*32 + hi*8]);
    }

    for (int ct = 0; ct < 12; ct++) {
        const float* W; int cw;
        if (ct < 4)      { W = Wni;   cw = ct*16; }
        else if (ct < 8) { W = Wnj;   cw = (ct-8+4)*16; }
        else             { W = Wnode; cw = (ct-8)*16; }
        __syncthreads();
#pragma unroll
        for (int q = 0; q < 8; q++) {
            int idx = threadIdx.x * 8 + q;      // 2048 = 16 cols x 128 k
            int col = idx >> 7, k = idx & 127;
            sW[col][k] = (__bf16)W[k*64 + cw + col];
        }
        __syncthreads();
        f32x4 acc = {0.f, 0.f, 0.f, 0.f};
#pragma unroll
        for (int kk = 0; kk < 4; kk++) {
            bf16x8 bfrag = *reinterpret_cast<const bf16x8*>(&sW[lo][kk*32 + hi*8]);
            acc = __builtin_amdgcn_mfma_f32_16x16x32_bf16(afrag[kk], bfrag, acc, 0, 0, 0);
        }
#pragma unroll
        for (int r = 0; r < 4; r++) {
            int row = rbase + hi*4 + r;
            if (row < NN) P[(size_t)row*PD + ct*16 + lo] = __float2bfloat16(acc[r]);
        }
    }
}

// ---------------- CSR build ----------------
__global__ void k_hist(const int* __restrict__ dst, int* __restrict__ counts, int e) {
    int i = blockIdx.x * blockDim.x + threadIdx.x;
    if (i < e) atomicAdd(&counts[dst[i]], 1);
}

__global__ __launch_bounds__(1024) void k_scan(const int* __restrict__ counts,
                                               int* __restrict__ offsets, int n) {
    __shared__ int wsum[16];
    __shared__ int chunk_carry;
    if (threadIdx.x == 0) chunk_carry = 0;
    __syncthreads();
    const int lane = threadIdx.x & 63;
    const int wid  = threadIdx.x >> 6;
    for (int base = 0; base < n; base += 8192) {
        const int i0 = base + threadIdx.x * 8;
        int v[8], tsum = 0;
#pragma unroll
        for (int j = 0; j < 8; j++) {
            int idx = i0 + j;
            v[j] = (idx < n) ? counts[idx] : 0;
            tsum += v[j];
        }
        int sc = tsum;
#pragma unroll
        for (int s = 1; s < 64; s <<= 1) {
            int t = __shfl_up(sc, s);
            if (lane >= s) sc += t;
        }
        if (lane == 63) wsum[wid] = sc;
        __syncthreads();
        int woff = 0;
        for (int k = 0; k < wid; k++) woff += wsum[k];
        int run = chunk_carry + woff + (sc - tsum);
#pragma unroll
        for (int j = 0; j < 8; j++) {
            int idx = i0 + j;
            if (idx < n) offsets[idx] = run;
            run += v[j];
        }
        __syncthreads();
        if (threadIdx.x == 1023) chunk_carry += woff + sc;
        __syncthreads();
    }
    if (threadIdx.x == 0) offsets[n] = chunk_carry;
}

__global__ void k_scatter(const int* __restrict__ dst, const int* __restrict__ offsets,
                          int* __restrict__ cursor, int* __restrict__ eidx, int e) {
    int i = blockIdx.x * blockDim.x + threadIdx.x;
    if (i < e) {
        int d = dst[i];
        int p = atomicAdd(&cursor[d], 1);
        eidx[offsets[d] + p] = i;
    }
}

// ---------------- K2: fused edge stage ----------------
// block = 64 edges / 4 waves. P_i/P_j gathered async into LDS (full-row 128B txns),
// f_out written via LDS transpose as contiguous 1KB wave stores.
__global__ __launch_bounds__(256) void k_edge(
    const float* __restrict__ efeats,
    const float* __restrict__ Wf,     // [32][64] f32
    const float* __restrict__ attn,   // [64] f32
    const float* __restrict__ bias,   // [64] f32
    const bf16* __restrict__ P,       // [NN][192] bf16
    const int* __restrict__ src, const int* __restrict__ dst,
    float* __restrict__ f_out,        // [NE][64] f32
    float* __restrict__ el)           // [NE][4]
{
    __shared__ __align__(16) __bf16 sP[2][64][64];   // 16KB, linear (global_load_lds dest)
    __shared__ int sIdx[2][64];
    const int t = threadIdx.x;
    const int lane = t & 63, wid = t >> 6;
    const int lo = lane & 15, hi = lane >> 4;
    const int e0 = blockIdx.x * 64;

    if (t < 64) sIdx[0][t] = src[e0 + t];
    else if (t < 128) sIdx[1][t - 64] = dst[e0 + t - 64];
    __syncthreads();

    // 1024 chunks of 16B (2 tables x 64 rows x 8 parts), 4 per thread.
    // chunk c: table=c>>9, row=(c>>3)&63, part=c&7; LDS byte offset = c*16 (wave-linear).
#pragma unroll
    for (int q = 0; q < 4; q++) {
        int c = t + q * 256;
        int table = c >> 9, row = (c >> 3) & 63, part = c & 7;
        const bf16* g = P + (size_t)sIdx[table][row] * PD + table * 64 + part * 8;
        __bf16* ldsbase = &sP[0][0][0] + (size_t)(c & ~63) * 8;   // wave-uniform
        async_copy16(g, ldsbase);
    }

    bf16x8 afrag = load8_f32_to_bf16(&efeats[(size_t)(e0 + wid*16 + lo)*DEIN + hi*8]);
    bf16x8 bfr[4];
#pragma unroll
    for (int ct = 0; ct < 4; ct++)
#pragma unroll
        for (int j = 0; j < 8; j++)
            bfr[ct][j] = (__bf16)Wf[(hi*8 + j)*64 + ct*16 + lo];

    __syncthreads();   // drains vmcnt (gathers in LDS) + barrier

    float v[4][4];     // [ct][r]
#pragma unroll
    for (int ct = 0; ct < 4; ct++) {
        f32x4 acc = {0.f, 0.f, 0.f, 0.f};
        acc = __builtin_amdgcn_mfma_f32_16x16x32_bf16(afrag, bfr[ct], acc, 0, 0, 0);
        const int c = ct*16 + lo;
        const float att = attn[c];
        const float bs  = bias[c];
#pragma unroll
        for (int r = 0; r < 4; r++) {
            const int lrow = wid*16 + hi*4 + r;
            float x = acc[r]
                    + __bfloat162float(sP[0][lrow][c])
                    + __bfloat162float(sP[1][lrow][c])
                    + bs;
            x = x > 0.f ? x : NEG_SLOPE * x;
            v[ct][r] = x;
            float s = x * att;
            s += __shfl_xor(s, 1);
            s += __shfl_xor(s, 2);
            s += __shfl_xor(s, 4);
            s += __shfl_xor(s, 8);
            if (lo == 0) el[(size_t)(e0 + lrow)*4 + ct] = s;
        }
    }

    __syncthreads();   // all waves done reading sP -> reuse as f32 transpose buffer
    float* sOut = reinterpret_cast<float*>(&sP[0][0][0]) + wid * 1024;  // 16x64 f32
#pragma unroll
    for (int ct = 0; ct < 4; ct++)
#pragma unroll
        for (int r = 0; r < 4; r++)
            sOut[(hi*4 + r)*64 + ct*16 + lo] = v[ct][r];
    // wave-local write->read; compiler inserts lgkmcnt waits
#pragma unroll
    for (int q = 0; q < 4; q++) {
        const int lrow = (lane >> 4) + q*4;
        const int c4   = (lane & 15) * 4;
        f32x4 o = *reinterpret_cast<const f32x4*>(&sOut[lrow*64 + c4]);
        *reinterpret_cast<f32x4*>(&f_out[(size_t)(e0 + wid*16 + lrow)*64 + c4]) = o;
    }
}

// ---------------- K4: per-dst-node online softmax + weighted aggregation ----------------
__global__ __launch_bounds__(256) void k_aggregate(
    const int* __restrict__ offsets, const int* __restrict__ eidx,
    const int* __restrict__ src, const float* __restrict__ el,
    const bf16* __restrict__ P, float* __restrict__ h_out)
{
    const int lane = threadIdx.x & 63;
    const int wid  = threadIdx.x >> 6;
    const int n = blockIdx.x * 4 + wid;
    if (n >= NN) return;
    const int h = lane >> 4;
    const int off0 = offsets[n], off1 = offsets[n + 1];
    float m = -3.0e38f, den = 0.f, acc = 0.f;
    for (int t = off0; t < off1; t++) {
        const int e = eidx[t];
        const int s = src[e];
        const float lv = el[(size_t)e*4 + h];
        const float p  = __bfloat162float(P[(size_t)s*PD + 128 + lane]);
        const float nm = fmaxf(m, lv);
        const float scale = __expf(m - nm);
        const float w = __expf(lv - nm);
        den = den * scale + w;
        acc = acc * scale + w * p;
        m = nm;
    }
    const float o = (off1 > off0) ? acc / den : 0.f;
    h_out[(size_t)n*64 + lane] = o;
}

extern "C" void kernel_launch(void* const* d_in, const int* in_sizes, int n_in,
                              void* d_out, int out_size, void* d_ws, size_t ws_size,
                              hipStream_t stream) {
    const float* nfeats = (const float*)d_in[0];
    const float* efeats = (const float*)d_in[1];
    const float* Wni    = (const float*)d_in[2];
    const float* Wnj    = (const float*)d_in[3];
    const float* Wfij   = (const float*)d_in[4];
    const float* Wnode  = (const float*)d_in[5];
    const float* attn   = (const float*)d_in[6];
    const float* bias   = (const float*)d_in[7];
    const int*   src    = (const int*)d_in[8];
    const int*   dst    = (const int*)d_in[9];

    float* h_out = (float*)d_out;                           // [NN*64]
    float* f_out = (float*)d_out + (size_t)NN * 64;         // [NE*64]

    char* ws = (char*)d_ws;
    size_t off = 0;
    auto carve = [&](size_t bytes) -> void* {
        void* p = ws + off;
        off = (off + bytes + 255) & ~(size_t)255;
        return p;
    };
    bf16*  P       = (bf16*) carve((size_t)NN * PD * sizeof(bf16));
    float* el      = (float*)carve((size_t)NE * 4 * sizeof(float));
    int*   counts  = (int*)  carve((size_t)2 * NN * sizeof(int));   // counts + cursor
    int*   cursor  = counts + NN;
    int*   offsets = (int*)  carve((size_t)(NN + 1) * sizeof(int));
    int*   eidx    = (int*)  carve((size_t)NE * sizeof(int));
    (void)ws_size; (void)in_sizes; (void)n_in; (void)out_size;

    hipMemsetAsync(counts, 0, (size_t)2 * NN * sizeof(int), stream);
    hipLaunchKernelGGL(k_node_gemm, dim3((NN + 63) / 64), dim3(256), 0, stream,
                       nfeats, Wni, Wnj, Wnode, P);
    hipLaunchKernelGGL(k_hist, dim3((NE + 255) / 256), dim3(256), 0, stream,
                       dst, counts, NE);
    hipLaunchKernelGGL(k_scan, dim3(1), dim3(1024), 0, stream,
                       counts, offsets, NN);
    hipLaunchKernelGGL(k_scatter, dim3((NE + 255) / 256), dim3(256), 0, stream,
                       dst, offsets, cursor, eidx, NE);
    hipLaunchKernelGGL(k_edge, dim3(NE / 64), dim3(256), 0, stream,
                       efeats, Wfij, attn, bias, P, src, dst, f_out, el);
    hipLaunchKernelGGL(k_aggregate, dim3((NN + 3) / 4), dim3(256), 0, stream,
                       offsets, eidx, src, el, P, h_out);
}